// Round 5
// baseline (697.910 us; speedup 1.0000x reference)
//
#include <hip/hip_runtime.h>
#include <hip/hip_fp16.h>
#include <cmath>

constexpr int D   = 96;
constexpr int C   = 12;
constexpr int P   = 11;   // 1 + 2*5
constexpr int VOX = D * D * D;        // 884736
constexpr int CELLS = 32 * 32 * 32;   // sort buckets (Morton 32^3)

// ---------------------------------------------------------------------------
// Transpose + downconvert: [P*C][x][y][z] f32 -> [P][x][y][z][C] fp16
// ---------------------------------------------------------------------------
__global__ __launch_bounds__(256) void transpose_fp16_kernel(
    const float* __restrict__ g, __half* __restrict__ gt) {
  constexpr int RPT = VOX / 4;
  int t = blockIdx.x * 256 + threadIdx.x;
  if (t >= P * RPT) return;
  int p = t / RPT;
  int r4 = (t - p * RPT) * 4;
  const float* src = g + (size_t)p * C * VOX + r4;

  float4 v[C];
#pragma unroll
  for (int c = 0; c < C; ++c)
    v[c] = *reinterpret_cast<const float4*>(src + (size_t)c * VOX);

  union { __half h[48]; uint4 u[6]; } pk;
#pragma unroll
  for (int j = 0; j < 4; ++j) {
#pragma unroll
    for (int c = 0; c < C; ++c) {
      float f = (j == 0) ? v[c].x : (j == 1) ? v[c].y : (j == 2) ? v[c].z : v[c].w;
      pk.h[j * C + c] = __float2half_rn(f);
    }
  }
  uint4* dst = reinterpret_cast<uint4*>(gt + ((size_t)p * VOX + r4) * C);
#pragma unroll
  for (int k = 0; k < 6; ++k) dst[k] = pk.u[k];
}

// ---------------------------------------------------------------------------
// Sort keys. Order A: spatial Morton cells. Order B: theta8-phase Morton
// cells, theta8 = 8*u mod 2pi (localizes f=4,8,16 gathers).
// ---------------------------------------------------------------------------
__device__ __forceinline__ unsigned spread5(unsigned v) {
  v &= 31u;
  v = (v | (v << 8)) & 0x100Fu;
  v = (v | (v << 4)) & 0x10C3u;
  v = (v | (v << 2)) & 0x1249u;
  return v;
}

__device__ __forceinline__ unsigned cellA_of(const float u[3]) {
  unsigned cc[3];
#pragma unroll
  for (int d = 0; d < 3; ++d) {
    int c = (int)((u[d] + 1.0f) * 16.0f);
    c = c < 0 ? 0 : (c > 31 ? 31 : c);
    cc[d] = (unsigned)c;
  }
  return spread5(cc[0]) | (spread5(cc[1]) << 1) | (spread5(cc[2]) << 2);
}

__device__ __forceinline__ unsigned cellB_of(const float u[3]) {
  unsigned cc[3];
#pragma unroll
  for (int d = 0; d < 3; ++d) {
    float v = u[d] * 1.27323954f;        // 8u / (2*pi)
    float f = v - floorf(v);             // phase in [0,1)
    int c = (int)(f * 32.0f);
    c = c < 0 ? 0 : (c > 31 ? 31 : c);
    cc[d] = (unsigned)c;
  }
  return spread5(cc[0]) | (spread5(cc[1]) << 1) | (spread5(cc[2]) << 2);
}

__device__ __forceinline__ void norm_u(const float* __restrict__ xyz, int n,
                                       const float* __restrict__ mn,
                                       const float* __restrict__ mx, float u[3]) {
#pragma unroll
  for (int d = 0; d < 3; ++d)
    u[d] = (xyz[3 * (size_t)n + d] - mn[d]) * (2.0f / (mx[d] - mn[d])) - 1.0f;
}

__global__ __launch_bounds__(256) void count_both_kernel(
    const float* __restrict__ xyz, const float* __restrict__ mn,
    const float* __restrict__ mx, unsigned* __restrict__ cntA,
    unsigned* __restrict__ cntB, int N, int doB) {
  int n = blockIdx.x * 256 + threadIdx.x;
  if (n >= N) return;
  float u[3];
  norm_u(xyz, n, mn, mx, u);
  atomicAdd(&cntA[cellA_of(u)], 1u);
  if (doB) atomicAdd(&cntB[cellB_of(u)], 1u);
}

// Per-block exclusive scan of one CELLS-array; block 0 -> A, block 1 -> B.
__global__ __launch_bounds__(1024) void scan2_kernel(
    const unsigned* __restrict__ cntA, unsigned* __restrict__ offA,
    const unsigned* __restrict__ cntB, unsigned* __restrict__ offB) {
  const unsigned* counts = (blockIdx.x == 0) ? cntA : cntB;
  unsigned* offsets = (blockIdx.x == 0) ? offA : offB;
  __shared__ unsigned part[1024];
  int t = threadIdx.x;
  unsigned base = t * (CELLS / 1024);
  unsigned local[CELLS / 1024];
  unsigned s = 0;
#pragma unroll
  for (int i = 0; i < CELLS / 1024; ++i) { local[i] = s; s += counts[base + i]; }
  part[t] = s;
  __syncthreads();
  for (int off = 1; off < 1024; off <<= 1) {
    unsigned v = (t >= off) ? part[t - off] : 0u;
    __syncthreads();
    part[t] += v;
    __syncthreads();
  }
  unsigned prev = (t == 0) ? 0u : part[t - 1];
#pragma unroll
  for (int i = 0; i < CELLS / 1024; ++i) offsets[base + i] = prev + local[i];
}

// Scatter normalized points into both sorted orders: rec = {ux,uy,uz,idx}.
__global__ __launch_bounds__(256) void scatter_both_kernel(
    const float* __restrict__ xyz, const float* __restrict__ mn,
    const float* __restrict__ mx, unsigned* __restrict__ offA,
    unsigned* __restrict__ offB, float4* __restrict__ sortedA,
    float4* __restrict__ sortedB, int N, int doB) {
  int n = blockIdx.x * 256 + threadIdx.x;
  if (n >= N) return;
  float u[3];
  norm_u(xyz, n, mn, mx, u);
  float4 rec;
  rec.x = u[0]; rec.y = u[1]; rec.z = u[2];
  rec.w = __uint_as_float((unsigned)n);
  unsigned sa = atomicAdd(&offA[cellA_of(u)], 1u);
  sortedA[sa] = rec;
  if (doB) {
    unsigned sb = atomicAdd(&offB[cellB_of(u)], 1u);
    sortedB[sb] = rec;
  }
}

// ---------------------------------------------------------------------------
// XCD-bijective chunked block swizzle (sorted blocks -> contiguous per-XCD).
// ---------------------------------------------------------------------------
__device__ __forceinline__ int swz_point(int N) {
  unsigned nwg = gridDim.x, bid = blockIdx.x;
  unsigned q = nwg / 8u, r = nwg % 8u;
  unsigned xcd = bid % 8u, j = bid / 8u;
  unsigned swz = (xcd < r ? xcd * (q + 1u) : r * (q + 1u) + (xcd - r) * q) + j;
  return (int)(swz * 256u + threadIdx.x);
}

// ---------------------------------------------------------------------------
// sample_lo: comps p=0..4 {id, sin1, cos1, sin2, cos2} on spatial order.
// Writes out = partial/11.
// ---------------------------------------------------------------------------
__global__ __launch_bounds__(256) void sample_lo_kernel(
    const float4* __restrict__ pts, const __half* __restrict__ g,
    float* __restrict__ out, int N) {
  int n = swz_point(N);
  if (n >= N) return;

  float4 rec = pts[n];
  unsigned oidx = __float_as_uint(rec.w);
  float u[3] = {rec.x, rec.y, rec.z};

  float acc[C];
#pragma unroll
  for (int c = 0; c < C; ++c) acc[c] = 0.0f;

  const ushort* gu = reinterpret_cast<const ushort*>(g);
  int p = 0;
  auto gather = [&](float ex, float ey, float ez) {
    float tz = (ez + 1.0f) * (0.5f * (D - 1));
    float ty = (ey + 1.0f) * (0.5f * (D - 1));
    float tx = (ex + 1.0f) * (0.5f * (D - 1));
    int z0 = (int)floorf(tz); z0 = z0 < 0 ? 0 : (z0 > D - 1 ? D - 1 : z0);
    int y0 = (int)floorf(ty); y0 = y0 < 0 ? 0 : (y0 > D - 1 ? D - 1 : y0);
    int x0 = (int)floorf(tx); x0 = x0 < 0 ? 0 : (x0 > D - 1 ? D - 1 : x0);
    int y1 = y0 + 1 > D - 1 ? D - 1 : y0 + 1;
    int x1 = x0 + 1 > D - 1 ? D - 1 : x0 + 1;
    float wz = tz - (float)z0, wy = ty - (float)y0, wx = tx - (float)x0;
    float wz0 = 1.0f - wz, wz1 = wz;
    float wy0 = 1.0f - wy, wy1 = wy;
    float wx0 = 1.0f - wx, wx1 = wx;

    size_t pbase = (size_t)p * VOX;
    const uint4* r00 = reinterpret_cast<const uint4*>(gu + (pbase + (size_t)((x0 * D + y0) * D + z0)) * C);
    const uint4* r01 = reinterpret_cast<const uint4*>(gu + (pbase + (size_t)((x0 * D + y1) * D + z0)) * C);
    const uint4* r10 = reinterpret_cast<const uint4*>(gu + (pbase + (size_t)((x1 * D + y0) * D + z0)) * C);
    const uint4* r11 = reinterpret_cast<const uint4*>(gu + (pbase + (size_t)((x1 * D + y1) * D + z0)) * C);

    uint4 a0 = r00[0], a1 = r00[1], a2 = r00[2];
    uint4 b0 = r01[0], b1 = r01[1], b2 = r01[2];
    uint4 c0 = r10[0], c1 = r10[1], c2 = r10[2];
    uint4 d0 = r11[0], d1 = r11[1], d2 = r11[2];

    auto acc2 = [&](unsigned lo, unsigned hi, float w0, float w1, int c) {
      __half2 hl = *reinterpret_cast<const __half2*>(&lo);
      __half2 hh = *reinterpret_cast<const __half2*>(&hi);
      float2 f0 = __half22float2(hl);
      float2 f1 = __half22float2(hh);
      acc[c]     = fmaf(w0, f0.x, fmaf(w1, f1.x, acc[c]));
      acc[c + 1] = fmaf(w0, f0.y, fmaf(w1, f1.y, acc[c + 1]));
    };
    auto region = [&](const uint4& q0, const uint4& q1, const uint4& q2, float wxy) {
      float w0 = wxy * wz0, w1 = wxy * wz1;
      acc2(q0.x, q1.z, w0, w1, 0);
      acc2(q0.y, q1.w, w0, w1, 2);
      acc2(q0.z, q2.x, w0, w1, 4);
      acc2(q0.w, q2.y, w0, w1, 6);
      acc2(q1.x, q2.z, w0, w1, 8);
      acc2(q1.y, q2.w, w0, w1, 10);
    };
    region(a0, a1, a2, wx0 * wy0);
    region(b0, b1, b2, wx0 * wy1);
    region(c0, c1, c2, wx1 * wy0);
    region(d0, d1, d2, wx1 * wy1);
    ++p;
  };

  gather(u[0], u[1], u[2]);                       // p=0 identity
  float s[3], co[3];
#pragma unroll
  for (int d = 0; d < 3; ++d) { s[d] = sinf(u[d]); co[d] = cosf(u[d]); }
  for (int f = 0; f < 2; ++f) {                   // f=1,2
    gather(s[0], s[1], s[2]);
    gather(co[0], co[1], co[2]);
    if (f < 1) {
#pragma unroll
      for (int d = 0; d < 3; ++d) {
        float ns = 2.0f * s[d] * co[d];
        float nc = 1.0f - 2.0f * s[d] * s[d];
        s[d] = ns; co[d] = nc;
      }
    }
  }

  constexpr float inv = 1.0f / (float)P;
  float4 r0, r1, r2;
  r0.x = acc[0] * inv;  r0.y = acc[1] * inv;  r0.z = acc[2] * inv;  r0.w = acc[3] * inv;
  r1.x = acc[4] * inv;  r1.y = acc[5] * inv;  r1.z = acc[6] * inv;  r1.w = acc[7] * inv;
  r2.x = acc[8] * inv;  r2.y = acc[9] * inv;  r2.z = acc[10] * inv; r2.w = acc[11] * inv;
  float4* o4 = reinterpret_cast<float4*>(out + (size_t)oidx * C);
  o4[0] = r0; o4[1] = r1; o4[2] = r2;
}

// ---------------------------------------------------------------------------
// sample_hi: comps p=5..10 {sin4, cos4, sin8, cos8, sin16, cos16} on the
// theta8 order. Read-modify-write out (runs after sample_lo on same stream).
// ---------------------------------------------------------------------------
__global__ __launch_bounds__(256) void sample_hi_kernel(
    const float4* __restrict__ pts, const __half* __restrict__ g,
    float* __restrict__ out, int N) {
  int n = swz_point(N);
  if (n >= N) return;

  float4 rec = pts[n];
  unsigned oidx = __float_as_uint(rec.w);
  float u[3] = {rec.x, rec.y, rec.z};

  float acc[C];
#pragma unroll
  for (int c = 0; c < C; ++c) acc[c] = 0.0f;

  const ushort* gu = reinterpret_cast<const ushort*>(g);
  int p = 5;
  auto gather = [&](float ex, float ey, float ez) {
    float tz = (ez + 1.0f) * (0.5f * (D - 1));
    float ty = (ey + 1.0f) * (0.5f * (D - 1));
    float tx = (ex + 1.0f) * (0.5f * (D - 1));
    int z0 = (int)floorf(tz); z0 = z0 < 0 ? 0 : (z0 > D - 1 ? D - 1 : z0);
    int y0 = (int)floorf(ty); y0 = y0 < 0 ? 0 : (y0 > D - 1 ? D - 1 : y0);
    int x0 = (int)floorf(tx); x0 = x0 < 0 ? 0 : (x0 > D - 1 ? D - 1 : x0);
    int y1 = y0 + 1 > D - 1 ? D - 1 : y0 + 1;
    int x1 = x0 + 1 > D - 1 ? D - 1 : x0 + 1;
    float wz = tz - (float)z0, wy = ty - (float)y0, wx = tx - (float)x0;
    float wz0 = 1.0f - wz, wz1 = wz;
    float wy0 = 1.0f - wy, wy1 = wy;
    float wx0 = 1.0f - wx, wx1 = wx;

    size_t pbase = (size_t)p * VOX;
    const uint4* r00 = reinterpret_cast<const uint4*>(gu + (pbase + (size_t)((x0 * D + y0) * D + z0)) * C);
    const uint4* r01 = reinterpret_cast<const uint4*>(gu + (pbase + (size_t)((x0 * D + y1) * D + z0)) * C);
    const uint4* r10 = reinterpret_cast<const uint4*>(gu + (pbase + (size_t)((x1 * D + y0) * D + z0)) * C);
    const uint4* r11 = reinterpret_cast<const uint4*>(gu + (pbase + (size_t)((x1 * D + y1) * D + z0)) * C);

    uint4 a0 = r00[0], a1 = r00[1], a2 = r00[2];
    uint4 b0 = r01[0], b1 = r01[1], b2 = r01[2];
    uint4 c0 = r10[0], c1 = r10[1], c2 = r10[2];
    uint4 d0 = r11[0], d1 = r11[1], d2 = r11[2];

    auto acc2 = [&](unsigned lo, unsigned hi, float w0, float w1, int c) {
      __half2 hl = *reinterpret_cast<const __half2*>(&lo);
      __half2 hh = *reinterpret_cast<const __half2*>(&hi);
      float2 f0 = __half22float2(hl);
      float2 f1 = __half22float2(hh);
      acc[c]     = fmaf(w0, f0.x, fmaf(w1, f1.x, acc[c]));
      acc[c + 1] = fmaf(w0, f0.y, fmaf(w1, f1.y, acc[c + 1]));
    };
    auto region = [&](const uint4& q0, const uint4& q1, const uint4& q2, float wxy) {
      float w0 = wxy * wz0, w1 = wxy * wz1;
      acc2(q0.x, q1.z, w0, w1, 0);
      acc2(q0.y, q1.w, w0, w1, 2);
      acc2(q0.z, q2.x, w0, w1, 4);
      acc2(q0.w, q2.y, w0, w1, 6);
      acc2(q1.x, q2.z, w0, w1, 8);
      acc2(q1.y, q2.w, w0, w1, 10);
    };
    region(a0, a1, a2, wx0 * wy0);
    region(b0, b1, b2, wx0 * wy1);
    region(c0, c1, c2, wx1 * wy0);
    region(d0, d1, d2, wx1 * wy1);
    ++p;
  };

  float s[3], co[3];
#pragma unroll
  for (int d = 0; d < 3; ++d) {
    float a = 4.0f * u[d];
    s[d] = sinf(a); co[d] = cosf(a);
  }
  for (int f = 0; f < 3; ++f) {                   // f=4,8,16
    gather(s[0], s[1], s[2]);
    gather(co[0], co[1], co[2]);
    if (f < 2) {
#pragma unroll
      for (int d = 0; d < 3; ++d) {
        float ns = 2.0f * s[d] * co[d];
        float nc = 1.0f - 2.0f * s[d] * s[d];
        s[d] = ns; co[d] = nc;
      }
    }
  }

  constexpr float inv = 1.0f / (float)P;
  float4* o4 = reinterpret_cast<float4*>(out + (size_t)oidx * C);
  float4 r0 = o4[0], r1 = o4[1], r2 = o4[2];
  r0.x += acc[0] * inv;  r0.y += acc[1] * inv;  r0.z += acc[2] * inv;  r0.w += acc[3] * inv;
  r1.x += acc[4] * inv;  r1.y += acc[5] * inv;  r1.z += acc[6] * inv;  r1.w += acc[7] * inv;
  r2.x += acc[8] * inv;  r2.y += acc[9] * inv;  r2.z += acc[10] * inv; r2.w += acc[11] * inv;
  o4[0] = r0; o4[1] = r1; o4[2] = r2;
}

// ---------------------------------------------------------------------------
// Fallback: unsorted fp16 path (round-3 behavior).
// ---------------------------------------------------------------------------
__global__ __launch_bounds__(256) void sample_fp16_kernel(
    const float* __restrict__ xyz, const __half* __restrict__ g,
    const float* __restrict__ xyz_min, const float* __restrict__ xyz_max,
    float* __restrict__ out, int N) {
  int n = blockIdx.x * 256 + threadIdx.x;
  if (n >= N) return;
  float u[3];
#pragma unroll
  for (int d = 0; d < 3; ++d) {
    float mn = xyz_min[d], mx = xyz_max[d];
    u[d] = (xyz[3 * (size_t)n + d] - mn) * (2.0f / (mx - mn)) - 1.0f;
  }
  float acc[C];
#pragma unroll
  for (int c = 0; c < C; ++c) acc[c] = 0.0f;
  const ushort* gu = reinterpret_cast<const ushort*>(g);
  int p = 0;
  auto gather = [&](float ex, float ey, float ez) {
    float tz = (ez + 1.0f) * (0.5f * (D - 1));
    float ty = (ey + 1.0f) * (0.5f * (D - 1));
    float tx = (ex + 1.0f) * (0.5f * (D - 1));
    int z0 = (int)floorf(tz); z0 = z0 < 0 ? 0 : (z0 > D - 1 ? D - 1 : z0);
    int y0 = (int)floorf(ty); y0 = y0 < 0 ? 0 : (y0 > D - 1 ? D - 1 : y0);
    int x0 = (int)floorf(tx); x0 = x0 < 0 ? 0 : (x0 > D - 1 ? D - 1 : x0);
    int y1 = y0 + 1 > D - 1 ? D - 1 : y0 + 1;
    int x1 = x0 + 1 > D - 1 ? D - 1 : x0 + 1;
    float wz = tz - (float)z0, wy = ty - (float)y0, wx = tx - (float)x0;
    float wz0 = 1.0f - wz, wz1 = wz;
    float wy0 = 1.0f - wy, wy1 = wy;
    float wx0 = 1.0f - wx, wx1 = wx;
    size_t pbase = (size_t)p * VOX;
    const uint4* r00 = reinterpret_cast<const uint4*>(gu + (pbase + (size_t)((x0 * D + y0) * D + z0)) * C);
    const uint4* r01 = reinterpret_cast<const uint4*>(gu + (pbase + (size_t)((x0 * D + y1) * D + z0)) * C);
    const uint4* r10 = reinterpret_cast<const uint4*>(gu + (pbase + (size_t)((x1 * D + y0) * D + z0)) * C);
    const uint4* r11 = reinterpret_cast<const uint4*>(gu + (pbase + (size_t)((x1 * D + y1) * D + z0)) * C);
    uint4 a0 = r00[0], a1 = r00[1], a2 = r00[2];
    uint4 b0 = r01[0], b1 = r01[1], b2 = r01[2];
    uint4 c0 = r10[0], c1 = r10[1], c2 = r10[2];
    uint4 d0 = r11[0], d1 = r11[1], d2 = r11[2];
    auto acc2 = [&](unsigned lo, unsigned hi, float w0, float w1, int c) {
      __half2 hl = *reinterpret_cast<const __half2*>(&lo);
      __half2 hh = *reinterpret_cast<const __half2*>(&hi);
      float2 f0 = __half22float2(hl);
      float2 f1 = __half22float2(hh);
      acc[c]     = fmaf(w0, f0.x, fmaf(w1, f1.x, acc[c]));
      acc[c + 1] = fmaf(w0, f0.y, fmaf(w1, f1.y, acc[c + 1]));
    };
    auto region = [&](const uint4& q0, const uint4& q1, const uint4& q2, float wxy) {
      float w0 = wxy * wz0, w1 = wxy * wz1;
      acc2(q0.x, q1.z, w0, w1, 0);
      acc2(q0.y, q1.w, w0, w1, 2);
      acc2(q0.z, q2.x, w0, w1, 4);
      acc2(q0.w, q2.y, w0, w1, 6);
      acc2(q1.x, q2.z, w0, w1, 8);
      acc2(q1.y, q2.w, w0, w1, 10);
    };
    region(a0, a1, a2, wx0 * wy0);
    region(b0, b1, b2, wx0 * wy1);
    region(c0, c1, c2, wx1 * wy0);
    region(d0, d1, d2, wx1 * wy1);
    ++p;
  };
  gather(u[0], u[1], u[2]);
  float s[3], co[3];
#pragma unroll
  for (int d = 0; d < 3; ++d) { s[d] = sinf(u[d]); co[d] = cosf(u[d]); }
  for (int f = 0; f < 5; ++f) {
    gather(s[0], s[1], s[2]);
    gather(co[0], co[1], co[2]);
    if (f < 4) {
#pragma unroll
      for (int d = 0; d < 3; ++d) {
        float ns = 2.0f * s[d] * co[d];
        float nc = 1.0f - 2.0f * s[d] * s[d];
        s[d] = ns; co[d] = nc;
      }
    }
  }
  constexpr float inv = 1.0f / (float)P;
  float4 r0, r1, r2;
  r0.x = acc[0] * inv;  r0.y = acc[1] * inv;  r0.z = acc[2] * inv;  r0.w = acc[3] * inv;
  r1.x = acc[4] * inv;  r1.y = acc[5] * inv;  r1.z = acc[6] * inv;  r1.w = acc[7] * inv;
  r2.x = acc[8] * inv;  r2.y = acc[9] * inv;  r2.z = acc[10] * inv; r2.w = acc[11] * inv;
  float4* o4 = reinterpret_cast<float4*>(out + (size_t)n * C);
  o4[0] = r0; o4[1] = r1; o4[2] = r2;
}

// Last-resort naive fp32 path.
__global__ __launch_bounds__(256) void sample_naive_kernel(
    const float* __restrict__ xyz, const float* __restrict__ g,
    const float* __restrict__ xyz_min, const float* __restrict__ xyz_max,
    float* __restrict__ out, int N) {
  int n = blockIdx.x * 256 + threadIdx.x;
  if (n >= N) return;
  float u[3];
#pragma unroll
  for (int d = 0; d < 3; ++d) {
    float mn = xyz_min[d], mx = xyz_max[d];
    u[d] = (xyz[3 * (size_t)n + d] - mn) * (2.0f / (mx - mn)) - 1.0f;
  }
  float acc[C];
#pragma unroll
  for (int c = 0; c < C; ++c) acc[c] = 0.0f;
  int p = 0;
  auto gather = [&](float ex, float ey, float ez) {
    float e[3] = {ez, ey, ex};
    int i0[3], i1[3]; float w[3];
#pragma unroll
    for (int d = 0; d < 3; ++d) {
      float t = (e[d] + 1.0f) * (0.5f * (D - 1));
      int a = (int)floorf(t);
      a = a < 0 ? 0 : (a > D - 1 ? D - 1 : a);
      int b = a + 1 > D - 1 ? D - 1 : a + 1;
      i0[d] = a; i1[d] = b; w[d] = t - (float)a;
    }
    const float* gp = g + (size_t)p * C * VOX;
    auto corner = [&](int iz, int iy, int ix, float wgt) {
      int o = (ix * D + iy) * D + iz;
#pragma unroll
      for (int c = 0; c < C; ++c) acc[c] += wgt * gp[(size_t)c * VOX + o];
    };
    corner(i0[0], i0[1], i0[2], (1 - w[0]) * (1 - w[1]) * (1 - w[2]));
    corner(i1[0], i0[1], i0[2], w[0] * (1 - w[1]) * (1 - w[2]));
    corner(i0[0], i1[1], i0[2], (1 - w[0]) * w[1] * (1 - w[2]));
    corner(i1[0], i1[1], i0[2], w[0] * w[1] * (1 - w[2]));
    corner(i0[0], i0[1], i1[2], (1 - w[0]) * (1 - w[1]) * w[2]);
    corner(i1[0], i0[1], i1[2], w[0] * (1 - w[1]) * w[2]);
    corner(i0[0], i1[1], i1[2], (1 - w[0]) * w[1] * w[2]);
    corner(i1[0], i1[1], i1[2], w[0] * w[1] * w[2]);
    ++p;
  };
  gather(u[0], u[1], u[2]);
  float s[3], co[3];
#pragma unroll
  for (int d = 0; d < 3; ++d) { s[d] = sinf(u[d]); co[d] = cosf(u[d]); }
  for (int f = 0; f < 5; ++f) {
    gather(s[0], s[1], s[2]);
    gather(co[0], co[1], co[2]);
    if (f < 4) {
#pragma unroll
      for (int d = 0; d < 3; ++d) {
        float ns = 2.0f * s[d] * co[d];
        float nc = 1.0f - 2.0f * s[d] * s[d];
        s[d] = ns; co[d] = nc;
      }
    }
  }
  constexpr float inv = 1.0f / (float)P;
#pragma unroll
  for (int c = 0; c < C; ++c) out[(size_t)n * C + c] = acc[c] * inv;
}

extern "C" void kernel_launch(void* const* d_in, const int* in_sizes, int n_in,
                              void* d_out, int out_size, void* d_ws, size_t ws_size,
                              hipStream_t stream) {
  const float* xyz = (const float*)d_in[0];
  const float* grid = (const float*)d_in[1];
  const float* mn = (const float*)d_in[2];
  const float* mx = (const float*)d_in[3];
  float* out = (float*)d_out;
  int N = in_sizes[0] / 3;

  size_t gt_bytes = (size_t)P * VOX * C * sizeof(__half);   // ~233.6 MB
  size_t sorted_bytes = (size_t)N * sizeof(float4);         // 12.8 MB
  size_t cnt_bytes = (size_t)CELLS * sizeof(unsigned);      // 128 KB

  size_t need_full = 2 * sorted_bytes + gt_bytes + 4 * cnt_bytes + 1024;
  size_t need_one  = sorted_bytes + gt_bytes + 2 * cnt_bytes + 1024;
  size_t need_min  = gt_bytes + 256;

  int sblocks = (N + 255) / 256;
  int tblocks = (P * (VOX / 4) + 255) / 256;

  if (ws_size >= need_one) {
    int doB = (ws_size >= need_full) ? 1 : 0;
    char* w = (char*)d_ws;
    float4* sortedA = (float4*)w;                     w += sorted_bytes;
    float4* sortedB = doB ? (float4*)w : sortedA;     if (doB) w += sorted_bytes;
    __half* gt      = (__half*)w;                     w += gt_bytes;
    unsigned* cntA  = (unsigned*)w;                   w += cnt_bytes;
    unsigned* offA  = (unsigned*)w;                   w += cnt_bytes;
    unsigned* cntB  = cntA;
    unsigned* offB  = offA;
    if (doB) {
      cntB = (unsigned*)w;  w += cnt_bytes;
      offB = (unsigned*)w;
    }

    transpose_fp16_kernel<<<tblocks, 256, 0, stream>>>(grid, gt);
    hipMemsetAsync(cntA, 0, (doB ? 4 : 2) * cnt_bytes, stream);  // zeroes cnt+off
    count_both_kernel<<<sblocks, 256, 0, stream>>>(xyz, mn, mx, cntA, cntB, N, doB);
    scan2_kernel<<<doB ? 2 : 1, 1024, 0, stream>>>(cntA, offA, cntB, offB);
    scatter_both_kernel<<<sblocks, 256, 0, stream>>>(xyz, mn, mx, offA, offB,
                                                     sortedA, sortedB, N, doB);
    sample_lo_kernel<<<sblocks, 256, 0, stream>>>(sortedA, gt, out, N);
    sample_hi_kernel<<<sblocks, 256, 0, stream>>>(sortedB, gt, out, N);
  } else if (ws_size >= need_min) {
    __half* gt = (__half*)d_ws;
    transpose_fp16_kernel<<<tblocks, 256, 0, stream>>>(grid, gt);
    sample_fp16_kernel<<<sblocks, 256, 0, stream>>>(xyz, gt, mn, mx, out, N);
  } else {
    sample_naive_kernel<<<sblocks, 256, 0, stream>>>(xyz, grid, mn, mx, out, N);
  }
}

// Round 6
// 586.902 us; speedup vs baseline: 1.1891x; 1.1891x over previous
//
#include <hip/hip_runtime.h>
#include <hip/hip_fp16.h>
#include <cmath>

constexpr int D   = 96;
constexpr int C   = 12;
constexpr int P   = 11;   // 1 + 2*5
constexpr int VOX = D * D * D;        // 884736
constexpr int CELLS = 32 * 32 * 32;   // Morton 32^3 sort buckets

// ---------------------------------------------------------------------------
// Morton cell key
// ---------------------------------------------------------------------------
__device__ __forceinline__ unsigned spread5(unsigned v) {
  v &= 31u;
  v = (v | (v << 8)) & 0x100Fu;
  v = (v | (v << 4)) & 0x10C3u;
  v = (v | (v << 2)) & 0x1249u;
  return v;
}

__device__ __forceinline__ unsigned cell_of_u(const float u[3]) {
  unsigned cc[3];
#pragma unroll
  for (int d = 0; d < 3; ++d) {
    int c = (int)((u[d] + 1.0f) * 16.0f);
    c = c < 0 ? 0 : (c > 31 ? 31 : c);
    cc[d] = (unsigned)c;
  }
  return spread5(cc[0]) | (spread5(cc[1]) << 1) | (spread5(cc[2]) << 2);
}

__device__ __forceinline__ void norm_u(const float* __restrict__ xyz, int n,
                                       const float* __restrict__ mn,
                                       const float* __restrict__ mx, float u[3]) {
#pragma unroll
  for (int d = 0; d < 3; ++d)
    u[d] = (xyz[3 * (size_t)n + d] - mn[d]) * (2.0f / (mx[d] - mn[d])) - 1.0f;
}

// ---------------------------------------------------------------------------
// Transpose+downconvert [P*C][x][y][z] f32 -> [P][x][y][z][C] fp16, with the
// histogram count fused in (threads t < N also bin their point).
// ---------------------------------------------------------------------------
__global__ __launch_bounds__(256) void transpose_count_kernel(
    const float* __restrict__ g, __half* __restrict__ gt,
    const float* __restrict__ xyz, const float* __restrict__ mn,
    const float* __restrict__ mx, unsigned* __restrict__ counts, int N) {
  constexpr int RPT = VOX / 4;
  int t = blockIdx.x * 256 + threadIdx.x;

  if (t < P * RPT) {
    int p = t / RPT;
    int r4 = (t - p * RPT) * 4;
    const float* src = g + (size_t)p * C * VOX + r4;
    float4 v[C];
#pragma unroll
    for (int c = 0; c < C; ++c)
      v[c] = *reinterpret_cast<const float4*>(src + (size_t)c * VOX);
    union { __half h[48]; uint4 u[6]; } pk;
#pragma unroll
    for (int j = 0; j < 4; ++j) {
#pragma unroll
      for (int c = 0; c < C; ++c) {
        float f = (j == 0) ? v[c].x : (j == 1) ? v[c].y : (j == 2) ? v[c].z : v[c].w;
        pk.h[j * C + c] = __float2half_rn(f);
      }
    }
    uint4* dst = reinterpret_cast<uint4*>(gt + ((size_t)p * VOX + r4) * C);
#pragma unroll
    for (int k = 0; k < 6; ++k) dst[k] = pk.u[k];
  }

  if (t < N) {
    float u[3];
    norm_u(xyz, t, mn, mx, u);
    atomicAdd(&counts[cell_of_u(u)], 1u);
  }
}

// Single-block exclusive scan of CELLS (=32768) counters.
__global__ __launch_bounds__(1024) void scan_kernel(
    const unsigned* __restrict__ counts, unsigned* __restrict__ offsets) {
  __shared__ unsigned part[1024];
  int t = threadIdx.x;
  unsigned base = t * (CELLS / 1024);
  unsigned local[CELLS / 1024];
  unsigned s = 0;
#pragma unroll
  for (int i = 0; i < CELLS / 1024; ++i) { local[i] = s; s += counts[base + i]; }
  part[t] = s;
  __syncthreads();
  for (int off = 1; off < 1024; off <<= 1) {
    unsigned v = (t >= off) ? part[t - off] : 0u;
    __syncthreads();
    part[t] += v;
    __syncthreads();
  }
  unsigned prev = (t == 0) ? 0u : part[t - 1];
#pragma unroll
  for (int i = 0; i < CELLS / 1024; ++i) offsets[base + i] = prev + local[i];
}

// Scatter normalized points into cell-sorted order: rec = {ux,uy,uz,idx}.
__global__ __launch_bounds__(256) void scatter_kernel(
    const float* __restrict__ xyz, const float* __restrict__ mn,
    const float* __restrict__ mx, unsigned* __restrict__ offsets,
    float4* __restrict__ sorted, int N) {
  int n = blockIdx.x * 256 + threadIdx.x;
  if (n >= N) return;
  float u[3];
  norm_u(xyz, n, mn, mx, u);
  unsigned slot = atomicAdd(&offsets[cell_of_u(u)], 1u);
  float4 rec;
  rec.x = u[0]; rec.y = u[1]; rec.z = u[2];
  rec.w = __uint_as_float((unsigned)n);
  sorted[slot] = rec;
}

// ---------------------------------------------------------------------------
// Sample kernel: 2 consecutive sorted points per thread. Per comp, issue all
// 24 region loads (12 per point) before consuming -> 2x in-flight loads/wave.
// ---------------------------------------------------------------------------
__global__ __launch_bounds__(256) void sample_pair_kernel(
    const float4* __restrict__ pts, const __half* __restrict__ g,
    float* __restrict__ out, int N) {
  // XCD-bijective chunked swizzle over blocks of 512 consecutive points.
  unsigned nwg = gridDim.x, bid = blockIdx.x;
  unsigned q = nwg / 8u, r = nwg % 8u;
  unsigned xcd = bid % 8u, j = bid / 8u;
  unsigned swz = (xcd < r ? xcd * (q + 1u) : r * (q + 1u) + (xcd - r) * q) + j;
  int n0 = (int)(swz * 512u + threadIdx.x * 2u);
  int n1 = n0 + 1;
  if (n0 >= N) return;
  bool hasB = (n1 < N);

  float4 recA = pts[n0];
  float4 recB = hasB ? pts[n1] : recA;
  unsigned oiA = __float_as_uint(recA.w);
  unsigned oiB = __float_as_uint(recB.w);
  float uA[3] = {recA.x, recA.y, recA.z};
  float uB[3] = {recB.x, recB.y, recB.z};

  float accA[C], accB[C];
#pragma unroll
  for (int c = 0; c < C; ++c) { accA[c] = 0.0f; accB[c] = 0.0f; }

  const ushort* gu = reinterpret_cast<const ushort*>(g);
  int p = 0;

  // One trilinear setup: returns 4 region pointers + weights via out-params.
  auto setup = [&](float ex, float ey, float ez, size_t pbase,
                   const uint4*& r00, const uint4*& r01,
                   const uint4*& r10, const uint4*& r11,
                   float& wz0, float& wz1, float w4[4]) {
    float tz = (ez + 1.0f) * (0.5f * (D - 1));
    float ty = (ey + 1.0f) * (0.5f * (D - 1));
    float tx = (ex + 1.0f) * (0.5f * (D - 1));
    int z0 = (int)floorf(tz); z0 = z0 < 0 ? 0 : (z0 > D - 1 ? D - 1 : z0);
    int y0 = (int)floorf(ty); y0 = y0 < 0 ? 0 : (y0 > D - 1 ? D - 1 : y0);
    int x0 = (int)floorf(tx); x0 = x0 < 0 ? 0 : (x0 > D - 1 ? D - 1 : x0);
    int y1 = y0 + 1 > D - 1 ? D - 1 : y0 + 1;
    int x1 = x0 + 1 > D - 1 ? D - 1 : x0 + 1;
    float wz = tz - (float)z0, wy = ty - (float)y0, wx = tx - (float)x0;
    wz0 = 1.0f - wz; wz1 = wz;
    float wy0 = 1.0f - wy, wy1 = wy;
    float wx0 = 1.0f - wx, wx1 = wx;
    w4[0] = wx0 * wy0; w4[1] = wx0 * wy1; w4[2] = wx1 * wy0; w4[3] = wx1 * wy1;
    r00 = reinterpret_cast<const uint4*>(gu + (pbase + (size_t)((x0 * D + y0) * D + z0)) * C);
    r01 = reinterpret_cast<const uint4*>(gu + (pbase + (size_t)((x0 * D + y1) * D + z0)) * C);
    r10 = reinterpret_cast<const uint4*>(gu + (pbase + (size_t)((x1 * D + y0) * D + z0)) * C);
    r11 = reinterpret_cast<const uint4*>(gu + (pbase + (size_t)((x1 * D + y1) * D + z0)) * C);
  };

  auto consume = [&](float* acc, const uint4& q0, const uint4& q1, const uint4& q2,
                     float wxy, float wz0, float wz1) {
    float w0 = wxy * wz0, w1 = wxy * wz1;
    auto acc2 = [&](unsigned lo, unsigned hi, int c) {
      __half2 hl = *reinterpret_cast<const __half2*>(&lo);
      __half2 hh = *reinterpret_cast<const __half2*>(&hi);
      float2 f0 = __half22float2(hl);
      float2 f1 = __half22float2(hh);
      acc[c]     = fmaf(w0, f0.x, fmaf(w1, f1.x, acc[c]));
      acc[c + 1] = fmaf(w0, f0.y, fmaf(w1, f1.y, acc[c + 1]));
    };
    acc2(q0.x, q1.z, 0);
    acc2(q0.y, q1.w, 2);
    acc2(q0.z, q2.x, 4);
    acc2(q0.w, q2.y, 6);
    acc2(q1.x, q2.z, 8);
    acc2(q1.y, q2.w, 10);
  };

  // Per comp: set up both points, issue 24 loads, then consume A then B.
  auto gather2 = [&](float exA, float eyA, float ezA,
                     float exB, float eyB, float ezB) {
    size_t pbase = (size_t)p * VOX;
    const uint4 *a00, *a01, *a10, *a11, *b00, *b01, *b10, *b11;
    float az0, az1, bz0, bz1, wA[4], wB[4];
    setup(exA, eyA, ezA, pbase, a00, a01, a10, a11, az0, az1, wA);
    setup(exB, eyB, ezB, pbase, b00, b01, b10, b11, bz0, bz1, wB);

    // Issue all 24 loads back-to-back (z0==95 overread is weight-0, in-bounds).
    uint4 A0 = a00[0], A1 = a00[1], A2 = a00[2];
    uint4 A3 = a01[0], A4 = a01[1], A5 = a01[2];
    uint4 A6 = a10[0], A7 = a10[1], A8 = a10[2];
    uint4 A9 = a11[0], Aa = a11[1], Ab = a11[2];
    uint4 B0 = b00[0], B1 = b00[1], B2 = b00[2];
    uint4 B3 = b01[0], B4 = b01[1], B5 = b01[2];
    uint4 B6 = b10[0], B7 = b10[1], B8 = b10[2];
    uint4 B9 = b11[0], Ba = b11[1], Bb = b11[2];

    consume(accA, A0, A1, A2, wA[0], az0, az1);
    consume(accA, A3, A4, A5, wA[1], az0, az1);
    consume(accA, A6, A7, A8, wA[2], az0, az1);
    consume(accA, A9, Aa, Ab, wA[3], az0, az1);
    consume(accB, B0, B1, B2, wB[0], bz0, bz1);
    consume(accB, B3, B4, B5, wB[1], bz0, bz1);
    consume(accB, B6, B7, B8, wB[2], bz0, bz1);
    consume(accB, B9, Ba, Bb, wB[3], bz0, bz1);
    ++p;
  };

  gather2(uA[0], uA[1], uA[2], uB[0], uB[1], uB[2]);   // p=0 identity

  float sA[3], cA[3], sB[3], cB[3];
#pragma unroll
  for (int d = 0; d < 3; ++d) {
    sA[d] = sinf(uA[d]); cA[d] = cosf(uA[d]);
    sB[d] = sinf(uB[d]); cB[d] = cosf(uB[d]);
  }
  for (int f = 0; f < 5; ++f) {                        // f = 1,2,4,8,16
    gather2(sA[0], sA[1], sA[2], sB[0], sB[1], sB[2]);
    gather2(cA[0], cA[1], cA[2], cB[0], cB[1], cB[2]);
    if (f < 4) {
#pragma unroll
      for (int d = 0; d < 3; ++d) {
        float nsA = 2.0f * sA[d] * cA[d];
        float ncA = 1.0f - 2.0f * sA[d] * sA[d];
        sA[d] = nsA; cA[d] = ncA;
        float nsB = 2.0f * sB[d] * cB[d];
        float ncB = 1.0f - 2.0f * sB[d] * sB[d];
        sB[d] = nsB; cB[d] = ncB;
      }
    }
  }

  constexpr float inv = 1.0f / (float)P;
  {
    float4 r0, r1, r2;
    r0.x = accA[0] * inv;  r0.y = accA[1] * inv;  r0.z = accA[2] * inv;  r0.w = accA[3] * inv;
    r1.x = accA[4] * inv;  r1.y = accA[5] * inv;  r1.z = accA[6] * inv;  r1.w = accA[7] * inv;
    r2.x = accA[8] * inv;  r2.y = accA[9] * inv;  r2.z = accA[10] * inv; r2.w = accA[11] * inv;
    float4* o4 = reinterpret_cast<float4*>(out + (size_t)oiA * C);
    o4[0] = r0; o4[1] = r1; o4[2] = r2;
  }
  if (hasB) {
    float4 r0, r1, r2;
    r0.x = accB[0] * inv;  r0.y = accB[1] * inv;  r0.z = accB[2] * inv;  r0.w = accB[3] * inv;
    r1.x = accB[4] * inv;  r1.y = accB[5] * inv;  r1.z = accB[6] * inv;  r1.w = accB[7] * inv;
    r2.x = accB[8] * inv;  r2.y = accB[9] * inv;  r2.z = accB[10] * inv; r2.w = accB[11] * inv;
    float4* o4 = reinterpret_cast<float4*>(out + (size_t)oiB * C);
    o4[0] = r0; o4[1] = r1; o4[2] = r2;
  }
}

// ---------------------------------------------------------------------------
// Fallback: unsorted fp16 path.
// ---------------------------------------------------------------------------
__global__ __launch_bounds__(256) void sample_fp16_kernel(
    const float* __restrict__ xyz, const __half* __restrict__ g,
    const float* __restrict__ xyz_min, const float* __restrict__ xyz_max,
    float* __restrict__ out, int N) {
  int n = blockIdx.x * 256 + threadIdx.x;
  if (n >= N) return;
  float u[3];
#pragma unroll
  for (int d = 0; d < 3; ++d) {
    float mn = xyz_min[d], mx = xyz_max[d];
    u[d] = (xyz[3 * (size_t)n + d] - mn) * (2.0f / (mx - mn)) - 1.0f;
  }
  float acc[C];
#pragma unroll
  for (int c = 0; c < C; ++c) acc[c] = 0.0f;
  const ushort* gu = reinterpret_cast<const ushort*>(g);
  int p = 0;
  auto gather = [&](float ex, float ey, float ez) {
    float tz = (ez + 1.0f) * (0.5f * (D - 1));
    float ty = (ey + 1.0f) * (0.5f * (D - 1));
    float tx = (ex + 1.0f) * (0.5f * (D - 1));
    int z0 = (int)floorf(tz); z0 = z0 < 0 ? 0 : (z0 > D - 1 ? D - 1 : z0);
    int y0 = (int)floorf(ty); y0 = y0 < 0 ? 0 : (y0 > D - 1 ? D - 1 : y0);
    int x0 = (int)floorf(tx); x0 = x0 < 0 ? 0 : (x0 > D - 1 ? D - 1 : x0);
    int y1 = y0 + 1 > D - 1 ? D - 1 : y0 + 1;
    int x1 = x0 + 1 > D - 1 ? D - 1 : x0 + 1;
    float wz = tz - (float)z0, wy = ty - (float)y0, wx = tx - (float)x0;
    float wz0 = 1.0f - wz, wz1 = wz;
    float wy0 = 1.0f - wy, wy1 = wy;
    float wx0 = 1.0f - wx, wx1 = wx;
    size_t pbase = (size_t)p * VOX;
    const uint4* r00 = reinterpret_cast<const uint4*>(gu + (pbase + (size_t)((x0 * D + y0) * D + z0)) * C);
    const uint4* r01 = reinterpret_cast<const uint4*>(gu + (pbase + (size_t)((x0 * D + y1) * D + z0)) * C);
    const uint4* r10 = reinterpret_cast<const uint4*>(gu + (pbase + (size_t)((x1 * D + y0) * D + z0)) * C);
    const uint4* r11 = reinterpret_cast<const uint4*>(gu + (pbase + (size_t)((x1 * D + y1) * D + z0)) * C);
    uint4 a0 = r00[0], a1 = r00[1], a2 = r00[2];
    uint4 b0 = r01[0], b1 = r01[1], b2 = r01[2];
    uint4 c0 = r10[0], c1 = r10[1], c2 = r10[2];
    uint4 d0 = r11[0], d1 = r11[1], d2 = r11[2];
    auto acc2 = [&](unsigned lo, unsigned hi, float w0, float w1, int c) {
      __half2 hl = *reinterpret_cast<const __half2*>(&lo);
      __half2 hh = *reinterpret_cast<const __half2*>(&hi);
      float2 f0 = __half22float2(hl);
      float2 f1 = __half22float2(hh);
      acc[c]     = fmaf(w0, f0.x, fmaf(w1, f1.x, acc[c]));
      acc[c + 1] = fmaf(w0, f0.y, fmaf(w1, f1.y, acc[c + 1]));
    };
    auto region = [&](const uint4& q0, const uint4& q1, const uint4& q2, float wxy) {
      float w0 = wxy * wz0, w1 = wxy * wz1;
      acc2(q0.x, q1.z, w0, w1, 0);
      acc2(q0.y, q1.w, w0, w1, 2);
      acc2(q0.z, q2.x, w0, w1, 4);
      acc2(q0.w, q2.y, w0, w1, 6);
      acc2(q1.x, q2.z, w0, w1, 8);
      acc2(q1.y, q2.w, w0, w1, 10);
    };
    region(a0, a1, a2, wx0 * wy0);
    region(b0, b1, b2, wx0 * wy1);
    region(c0, c1, c2, wx1 * wy0);
    region(d0, d1, d2, wx1 * wy1);
    ++p;
  };
  gather(u[0], u[1], u[2]);
  float s[3], co[3];
#pragma unroll
  for (int d = 0; d < 3; ++d) { s[d] = sinf(u[d]); co[d] = cosf(u[d]); }
  for (int f = 0; f < 5; ++f) {
    gather(s[0], s[1], s[2]);
    gather(co[0], co[1], co[2]);
    if (f < 4) {
#pragma unroll
      for (int d = 0; d < 3; ++d) {
        float ns = 2.0f * s[d] * co[d];
        float nc = 1.0f - 2.0f * s[d] * s[d];
        s[d] = ns; co[d] = nc;
      }
    }
  }
  constexpr float inv = 1.0f / (float)P;
  float4 r0, r1, r2;
  r0.x = acc[0] * inv;  r0.y = acc[1] * inv;  r0.z = acc[2] * inv;  r0.w = acc[3] * inv;
  r1.x = acc[4] * inv;  r1.y = acc[5] * inv;  r1.z = acc[6] * inv;  r1.w = acc[7] * inv;
  r2.x = acc[8] * inv;  r2.y = acc[9] * inv;  r2.z = acc[10] * inv; r2.w = acc[11] * inv;
  float4* o4 = reinterpret_cast<float4*>(out + (size_t)n * C);
  o4[0] = r0; o4[1] = r1; o4[2] = r2;
}

// Last-resort naive fp32 path.
__global__ __launch_bounds__(256) void sample_naive_kernel(
    const float* __restrict__ xyz, const float* __restrict__ g,
    const float* __restrict__ xyz_min, const float* __restrict__ xyz_max,
    float* __restrict__ out, int N) {
  int n = blockIdx.x * 256 + threadIdx.x;
  if (n >= N) return;
  float u[3];
#pragma unroll
  for (int d = 0; d < 3; ++d) {
    float mn = xyz_min[d], mx = xyz_max[d];
    u[d] = (xyz[3 * (size_t)n + d] - mn) * (2.0f / (mx - mn)) - 1.0f;
  }
  float acc[C];
#pragma unroll
  for (int c = 0; c < C; ++c) acc[c] = 0.0f;
  int p = 0;
  auto gather = [&](float ex, float ey, float ez) {
    float e[3] = {ez, ey, ex};
    int i0[3], i1[3]; float w[3];
#pragma unroll
    for (int d = 0; d < 3; ++d) {
      float t = (e[d] + 1.0f) * (0.5f * (D - 1));
      int a = (int)floorf(t);
      a = a < 0 ? 0 : (a > D - 1 ? D - 1 : a);
      int b = a + 1 > D - 1 ? D - 1 : a + 1;
      i0[d] = a; i1[d] = b; w[d] = t - (float)a;
    }
    const float* gp = g + (size_t)p * C * VOX;
    auto corner = [&](int iz, int iy, int ix, float wgt) {
      int o = (ix * D + iy) * D + iz;
#pragma unroll
      for (int c = 0; c < C; ++c) acc[c] += wgt * gp[(size_t)c * VOX + o];
    };
    corner(i0[0], i0[1], i0[2], (1 - w[0]) * (1 - w[1]) * (1 - w[2]));
    corner(i1[0], i0[1], i0[2], w[0] * (1 - w[1]) * (1 - w[2]));
    corner(i0[0], i1[1], i0[2], (1 - w[0]) * w[1] * (1 - w[2]));
    corner(i1[0], i1[1], i0[2], w[0] * w[1] * (1 - w[2]));
    corner(i0[0], i0[1], i1[2], (1 - w[0]) * (1 - w[1]) * w[2]);
    corner(i1[0], i0[1], i1[2], w[0] * (1 - w[1]) * w[2]);
    corner(i0[0], i1[1], i1[2], (1 - w[0]) * w[1] * w[2]);
    corner(i1[0], i1[1], i1[2], w[0] * w[1] * w[2]);
    ++p;
  };
  gather(u[0], u[1], u[2]);
  float s[3], co[3];
#pragma unroll
  for (int d = 0; d < 3; ++d) { s[d] = sinf(u[d]); co[d] = cosf(u[d]); }
  for (int f = 0; f < 5; ++f) {
    gather(s[0], s[1], s[2]);
    gather(co[0], co[1], co[2]);
    if (f < 4) {
#pragma unroll
      for (int d = 0; d < 3; ++d) {
        float ns = 2.0f * s[d] * co[d];
        float nc = 1.0f - 2.0f * s[d] * s[d];
        s[d] = ns; co[d] = nc;
      }
    }
  }
  constexpr float inv = 1.0f / (float)P;
#pragma unroll
  for (int c = 0; c < C; ++c) out[(size_t)n * C + c] = acc[c] * inv;
}

extern "C" void kernel_launch(void* const* d_in, const int* in_sizes, int n_in,
                              void* d_out, int out_size, void* d_ws, size_t ws_size,
                              hipStream_t stream) {
  const float* xyz = (const float*)d_in[0];
  const float* grid = (const float*)d_in[1];
  const float* mn = (const float*)d_in[2];
  const float* mx = (const float*)d_in[3];
  float* out = (float*)d_out;
  int N = in_sizes[0] / 3;

  size_t gt_bytes = (size_t)P * VOX * C * sizeof(__half);   // ~233.6 MB
  size_t sorted_bytes = (size_t)N * sizeof(float4);         // 12.8 MB
  size_t cnt_bytes = (size_t)CELLS * sizeof(unsigned);      // 128 KB

  size_t need_sorted = sorted_bytes + gt_bytes + 2 * cnt_bytes + 1024;
  size_t need_min = gt_bytes + 256;

  int sblocks = (N + 255) / 256;
  int tblocks = (P * (VOX / 4) + 255) / 256;   // covers N too (2.43M > 800k)

  if (ws_size >= need_sorted) {
    char* w = (char*)d_ws;
    float4*   sorted  = (float4*)w;   w += sorted_bytes;
    __half*   gt      = (__half*)w;   w += gt_bytes;
    unsigned* counts  = (unsigned*)w; w += cnt_bytes;
    unsigned* offsets = (unsigned*)w;

    hipMemsetAsync(counts, 0, cnt_bytes, stream);
    transpose_count_kernel<<<tblocks, 256, 0, stream>>>(grid, gt, xyz, mn, mx,
                                                        counts, N);
    scan_kernel<<<1, 1024, 0, stream>>>(counts, offsets);
    scatter_kernel<<<sblocks, 256, 0, stream>>>(xyz, mn, mx, offsets, sorted, N);
    int pblocks = (N + 511) / 512;
    sample_pair_kernel<<<pblocks, 256, 0, stream>>>(sorted, gt, out, N);
  } else if (ws_size >= need_min) {
    __half* gt = (__half*)d_ws;
    transpose_count_kernel<<<tblocks, 256, 0, stream>>>(grid, gt, xyz, mn, mx,
                                                        nullptr, 0);
    sample_fp16_kernel<<<sblocks, 256, 0, stream>>>(xyz, gt, mn, mx, out, N);
  } else {
    sample_naive_kernel<<<sblocks, 256, 0, stream>>>(xyz, grid, mn, mx, out, N);
  }
}

// Round 7
// 586.523 us; speedup vs baseline: 1.1899x; 1.0006x over previous
//
#include <hip/hip_runtime.h>
#include <hip/hip_fp16.h>
#include <cmath>

constexpr int D   = 96;
constexpr int C   = 12;
constexpr int P   = 11;   // 1 + 2*5
constexpr int VOX = D * D * D;        // 884736
constexpr int CELLS = 32 * 32 * 32;   // Morton 32^3 sort buckets

// ---------------------------------------------------------------------------
// Morton cell key
// ---------------------------------------------------------------------------
__device__ __forceinline__ unsigned spread5(unsigned v) {
  v &= 31u;
  v = (v | (v << 8)) & 0x100Fu;
  v = (v | (v << 4)) & 0x10C3u;
  v = (v | (v << 2)) & 0x1249u;
  return v;
}

__device__ __forceinline__ unsigned cell_of_u(const float u[3]) {
  unsigned cc[3];
#pragma unroll
  for (int d = 0; d < 3; ++d) {
    int c = (int)((u[d] + 1.0f) * 16.0f);
    c = c < 0 ? 0 : (c > 31 ? 31 : c);
    cc[d] = (unsigned)c;
  }
  return spread5(cc[0]) | (spread5(cc[1]) << 1) | (spread5(cc[2]) << 2);
}

__device__ __forceinline__ void norm_u(const float* __restrict__ xyz, int n,
                                       const float* __restrict__ mn,
                                       const float* __restrict__ mx, float u[3]) {
#pragma unroll
  for (int d = 0; d < 3; ++d)
    u[d] = (xyz[3 * (size_t)n + d] - mn[d]) * (2.0f / (mx[d] - mn[d])) - 1.0f;
}

// ---------------------------------------------------------------------------
// Transpose+downconvert [P*C][x][y][z] f32 -> [P][x][y][z][C] fp16, with the
// histogram count fused in (threads t < N also bin their point).
// ---------------------------------------------------------------------------
__global__ __launch_bounds__(256) void transpose_count_kernel(
    const float* __restrict__ g, __half* __restrict__ gt,
    const float* __restrict__ xyz, const float* __restrict__ mn,
    const float* __restrict__ mx, unsigned* __restrict__ counts, int N) {
  constexpr int RPT = VOX / 4;
  int t = blockIdx.x * 256 + threadIdx.x;

  if (t < P * RPT) {
    int p = t / RPT;
    int r4 = (t - p * RPT) * 4;
    const float* src = g + (size_t)p * C * VOX + r4;
    float4 v[C];
#pragma unroll
    for (int c = 0; c < C; ++c)
      v[c] = *reinterpret_cast<const float4*>(src + (size_t)c * VOX);
    union { __half h[48]; uint4 u[6]; } pk;
#pragma unroll
    for (int j = 0; j < 4; ++j) {
#pragma unroll
      for (int c = 0; c < C; ++c) {
        float f = (j == 0) ? v[c].x : (j == 1) ? v[c].y : (j == 2) ? v[c].z : v[c].w;
        pk.h[j * C + c] = __float2half_rn(f);
      }
    }
    uint4* dst = reinterpret_cast<uint4*>(gt + ((size_t)p * VOX + r4) * C);
#pragma unroll
    for (int k = 0; k < 6; ++k) dst[k] = pk.u[k];
  }

  if (t < N) {
    float u[3];
    norm_u(xyz, t, mn, mx, u);
    atomicAdd(&counts[cell_of_u(u)], 1u);
  }
}

// Single-block exclusive scan of CELLS (=32768) counters.
__global__ __launch_bounds__(1024) void scan_kernel(
    const unsigned* __restrict__ counts, unsigned* __restrict__ offsets) {
  __shared__ unsigned part[1024];
  int t = threadIdx.x;
  unsigned base = t * (CELLS / 1024);
  unsigned local[CELLS / 1024];
  unsigned s = 0;
#pragma unroll
  for (int i = 0; i < CELLS / 1024; ++i) { local[i] = s; s += counts[base + i]; }
  part[t] = s;
  __syncthreads();
  for (int off = 1; off < 1024; off <<= 1) {
    unsigned v = (t >= off) ? part[t - off] : 0u;
    __syncthreads();
    part[t] += v;
    __syncthreads();
  }
  unsigned prev = (t == 0) ? 0u : part[t - 1];
#pragma unroll
  for (int i = 0; i < CELLS / 1024; ++i) offsets[base + i] = prev + local[i];
}

// Scatter normalized points into cell-sorted order: rec = {ux,uy,uz,idx}.
__global__ __launch_bounds__(256) void scatter_kernel(
    const float* __restrict__ xyz, const float* __restrict__ mn,
    const float* __restrict__ mx, unsigned* __restrict__ offsets,
    float4* __restrict__ sorted, int N) {
  int n = blockIdx.x * 256 + threadIdx.x;
  if (n >= N) return;
  float u[3];
  norm_u(xyz, n, mn, mx, u);
  unsigned slot = atomicAdd(&offsets[cell_of_u(u)], 1u);
  float4 rec;
  rec.x = u[0]; rec.y = u[1]; rec.z = u[2];
  rec.w = __uint_as_float((unsigned)n);
  sorted[slot] = rec;
}

// ---------------------------------------------------------------------------
// Sample kernel: 2 consecutive sorted points per thread. Per comp, issue all
// 24 region loads (12 per point) before consuming -> 2x in-flight loads/wave.
// ---------------------------------------------------------------------------
__global__ __launch_bounds__(256) void sample_pair_kernel(
    const float4* __restrict__ pts, const __half* __restrict__ g,
    float* __restrict__ out, int N) {
  // XCD-bijective chunked swizzle over blocks of 512 consecutive points.
  unsigned nwg = gridDim.x, bid = blockIdx.x;
  unsigned q = nwg / 8u, r = nwg % 8u;
  unsigned xcd = bid % 8u, j = bid / 8u;
  unsigned swz = (xcd < r ? xcd * (q + 1u) : r * (q + 1u) + (xcd - r) * q) + j;
  int n0 = (int)(swz * 512u + threadIdx.x * 2u);
  int n1 = n0 + 1;
  if (n0 >= N) return;
  bool hasB = (n1 < N);

  float4 recA = pts[n0];
  float4 recB = hasB ? pts[n1] : recA;
  unsigned oiA = __float_as_uint(recA.w);
  unsigned oiB = __float_as_uint(recB.w);
  float uA[3] = {recA.x, recA.y, recA.z};
  float uB[3] = {recB.x, recB.y, recB.z};

  float accA[C], accB[C];
#pragma unroll
  for (int c = 0; c < C; ++c) { accA[c] = 0.0f; accB[c] = 0.0f; }

  const ushort* gu = reinterpret_cast<const ushort*>(g);
  int p = 0;

  // One trilinear setup: returns 4 region pointers + weights via out-params.
  auto setup = [&](float ex, float ey, float ez, size_t pbase,
                   const uint4*& r00, const uint4*& r01,
                   const uint4*& r10, const uint4*& r11,
                   float& wz0, float& wz1, float w4[4]) {
    float tz = (ez + 1.0f) * (0.5f * (D - 1));
    float ty = (ey + 1.0f) * (0.5f * (D - 1));
    float tx = (ex + 1.0f) * (0.5f * (D - 1));
    int z0 = (int)floorf(tz); z0 = z0 < 0 ? 0 : (z0 > D - 1 ? D - 1 : z0);
    int y0 = (int)floorf(ty); y0 = y0 < 0 ? 0 : (y0 > D - 1 ? D - 1 : y0);
    int x0 = (int)floorf(tx); x0 = x0 < 0 ? 0 : (x0 > D - 1 ? D - 1 : x0);
    int y1 = y0 + 1 > D - 1 ? D - 1 : y0 + 1;
    int x1 = x0 + 1 > D - 1 ? D - 1 : x0 + 1;
    float wz = tz - (float)z0, wy = ty - (float)y0, wx = tx - (float)x0;
    wz0 = 1.0f - wz; wz1 = wz;
    float wy0 = 1.0f - wy, wy1 = wy;
    float wx0 = 1.0f - wx, wx1 = wx;
    w4[0] = wx0 * wy0; w4[1] = wx0 * wy1; w4[2] = wx1 * wy0; w4[3] = wx1 * wy1;
    r00 = reinterpret_cast<const uint4*>(gu + (pbase + (size_t)((x0 * D + y0) * D + z0)) * C);
    r01 = reinterpret_cast<const uint4*>(gu + (pbase + (size_t)((x0 * D + y1) * D + z0)) * C);
    r10 = reinterpret_cast<const uint4*>(gu + (pbase + (size_t)((x1 * D + y0) * D + z0)) * C);
    r11 = reinterpret_cast<const uint4*>(gu + (pbase + (size_t)((x1 * D + y1) * D + z0)) * C);
  };

  auto consume = [&](float* acc, const uint4& q0, const uint4& q1, const uint4& q2,
                     float wxy, float wz0, float wz1) {
    float w0 = wxy * wz0, w1 = wxy * wz1;
    auto acc2 = [&](unsigned lo, unsigned hi, int c) {
      __half2 hl = *reinterpret_cast<const __half2*>(&lo);
      __half2 hh = *reinterpret_cast<const __half2*>(&hi);
      float2 f0 = __half22float2(hl);
      float2 f1 = __half22float2(hh);
      acc[c]     = fmaf(w0, f0.x, fmaf(w1, f1.x, acc[c]));
      acc[c + 1] = fmaf(w0, f0.y, fmaf(w1, f1.y, acc[c + 1]));
    };
    acc2(q0.x, q1.z, 0);
    acc2(q0.y, q1.w, 2);
    acc2(q0.z, q2.x, 4);
    acc2(q0.w, q2.y, 6);
    acc2(q1.x, q2.z, 8);
    acc2(q1.y, q2.w, 10);
  };

  // Per comp: set up both points, issue 24 loads, then consume A then B.
  auto gather2 = [&](float exA, float eyA, float ezA,
                     float exB, float eyB, float ezB) {
    size_t pbase = (size_t)p * VOX;
    const uint4 *a00, *a01, *a10, *a11, *b00, *b01, *b10, *b11;
    float az0, az1, bz0, bz1, wA[4], wB[4];
    setup(exA, eyA, ezA, pbase, a00, a01, a10, a11, az0, az1, wA);
    setup(exB, eyB, ezB, pbase, b00, b01, b10, b11, bz0, bz1, wB);

    // Issue all 24 loads back-to-back (z0==95 overread is weight-0, in-bounds).
    uint4 A0 = a00[0], A1 = a00[1], A2 = a00[2];
    uint4 A3 = a01[0], A4 = a01[1], A5 = a01[2];
    uint4 A6 = a10[0], A7 = a10[1], A8 = a10[2];
    uint4 A9 = a11[0], Aa = a11[1], Ab = a11[2];
    uint4 B0 = b00[0], B1 = b00[1], B2 = b00[2];
    uint4 B3 = b01[0], B4 = b01[1], B5 = b01[2];
    uint4 B6 = b10[0], B7 = b10[1], B8 = b10[2];
    uint4 B9 = b11[0], Ba = b11[1], Bb = b11[2];

    consume(accA, A0, A1, A2, wA[0], az0, az1);
    consume(accA, A3, A4, A5, wA[1], az0, az1);
    consume(accA, A6, A7, A8, wA[2], az0, az1);
    consume(accA, A9, Aa, Ab, wA[3], az0, az1);
    consume(accB, B0, B1, B2, wB[0], bz0, bz1);
    consume(accB, B3, B4, B5, wB[1], bz0, bz1);
    consume(accB, B6, B7, B8, wB[2], bz0, bz1);
    consume(accB, B9, Ba, Bb, wB[3], bz0, bz1);
    ++p;
  };

  gather2(uA[0], uA[1], uA[2], uB[0], uB[1], uB[2]);   // p=0 identity

  float sA[3], cA[3], sB[3], cB[3];
#pragma unroll
  for (int d = 0; d < 3; ++d) {
    sA[d] = sinf(uA[d]); cA[d] = cosf(uA[d]);
    sB[d] = sinf(uB[d]); cB[d] = cosf(uB[d]);
  }
  for (int f = 0; f < 5; ++f) {                        // f = 1,2,4,8,16
    gather2(sA[0], sA[1], sA[2], sB[0], sB[1], sB[2]);
    gather2(cA[0], cA[1], cA[2], cB[0], cB[1], cB[2]);
    if (f < 4) {
#pragma unroll
      for (int d = 0; d < 3; ++d) {
        float nsA = 2.0f * sA[d] * cA[d];
        float ncA = 1.0f - 2.0f * sA[d] * sA[d];
        sA[d] = nsA; cA[d] = ncA;
        float nsB = 2.0f * sB[d] * cB[d];
        float ncB = 1.0f - 2.0f * sB[d] * sB[d];
        sB[d] = nsB; cB[d] = ncB;
      }
    }
  }

  constexpr float inv = 1.0f / (float)P;
  {
    float4 r0, r1, r2;
    r0.x = accA[0] * inv;  r0.y = accA[1] * inv;  r0.z = accA[2] * inv;  r0.w = accA[3] * inv;
    r1.x = accA[4] * inv;  r1.y = accA[5] * inv;  r1.z = accA[6] * inv;  r1.w = accA[7] * inv;
    r2.x = accA[8] * inv;  r2.y = accA[9] * inv;  r2.z = accA[10] * inv; r2.w = accA[11] * inv;
    float4* o4 = reinterpret_cast<float4*>(out + (size_t)oiA * C);
    o4[0] = r0; o4[1] = r1; o4[2] = r2;
  }
  if (hasB) {
    float4 r0, r1, r2;
    r0.x = accB[0] * inv;  r0.y = accB[1] * inv;  r0.z = accB[2] * inv;  r0.w = accB[3] * inv;
    r1.x = accB[4] * inv;  r1.y = accB[5] * inv;  r1.z = accB[6] * inv;  r1.w = accB[7] * inv;
    r2.x = accB[8] * inv;  r2.y = accB[9] * inv;  r2.z = accB[10] * inv; r2.w = accB[11] * inv;
    float4* o4 = reinterpret_cast<float4*>(out + (size_t)oiB * C);
    o4[0] = r0; o4[1] = r1; o4[2] = r2;
  }
}

// ---------------------------------------------------------------------------
// Fallback: unsorted fp16 path.
// ---------------------------------------------------------------------------
__global__ __launch_bounds__(256) void sample_fp16_kernel(
    const float* __restrict__ xyz, const __half* __restrict__ g,
    const float* __restrict__ xyz_min, const float* __restrict__ xyz_max,
    float* __restrict__ out, int N) {
  int n = blockIdx.x * 256 + threadIdx.x;
  if (n >= N) return;
  float u[3];
#pragma unroll
  for (int d = 0; d < 3; ++d) {
    float mn = xyz_min[d], mx = xyz_max[d];
    u[d] = (xyz[3 * (size_t)n + d] - mn) * (2.0f / (mx - mn)) - 1.0f;
  }
  float acc[C];
#pragma unroll
  for (int c = 0; c < C; ++c) acc[c] = 0.0f;
  const ushort* gu = reinterpret_cast<const ushort*>(g);
  int p = 0;
  auto gather = [&](float ex, float ey, float ez) {
    float tz = (ez + 1.0f) * (0.5f * (D - 1));
    float ty = (ey + 1.0f) * (0.5f * (D - 1));
    float tx = (ex + 1.0f) * (0.5f * (D - 1));
    int z0 = (int)floorf(tz); z0 = z0 < 0 ? 0 : (z0 > D - 1 ? D - 1 : z0);
    int y0 = (int)floorf(ty); y0 = y0 < 0 ? 0 : (y0 > D - 1 ? D - 1 : y0);
    int x0 = (int)floorf(tx); x0 = x0 < 0 ? 0 : (x0 > D - 1 ? D - 1 : x0);
    int y1 = y0 + 1 > D - 1 ? D - 1 : y0 + 1;
    int x1 = x0 + 1 > D - 1 ? D - 1 : x0 + 1;
    float wz = tz - (float)z0, wy = ty - (float)y0, wx = tx - (float)x0;
    float wz0 = 1.0f - wz, wz1 = wz;
    float wy0 = 1.0f - wy, wy1 = wy;
    float wx0 = 1.0f - wx, wx1 = wx;
    size_t pbase = (size_t)p * VOX;
    const uint4* r00 = reinterpret_cast<const uint4*>(gu + (pbase + (size_t)((x0 * D + y0) * D + z0)) * C);
    const uint4* r01 = reinterpret_cast<const uint4*>(gu + (pbase + (size_t)((x0 * D + y1) * D + z0)) * C);
    const uint4* r10 = reinterpret_cast<const uint4*>(gu + (pbase + (size_t)((x1 * D + y0) * D + z0)) * C);
    const uint4* r11 = reinterpret_cast<const uint4*>(gu + (pbase + (size_t)((x1 * D + y1) * D + z0)) * C);
    uint4 a0 = r00[0], a1 = r00[1], a2 = r00[2];
    uint4 b0 = r01[0], b1 = r01[1], b2 = r01[2];
    uint4 c0 = r10[0], c1 = r10[1], c2 = r10[2];
    uint4 d0 = r11[0], d1 = r11[1], d2 = r11[2];
    auto acc2 = [&](unsigned lo, unsigned hi, float w0, float w1, int c) {
      __half2 hl = *reinterpret_cast<const __half2*>(&lo);
      __half2 hh = *reinterpret_cast<const __half2*>(&hi);
      float2 f0 = __half22float2(hl);
      float2 f1 = __half22float2(hh);
      acc[c]     = fmaf(w0, f0.x, fmaf(w1, f1.x, acc[c]));
      acc[c + 1] = fmaf(w0, f0.y, fmaf(w1, f1.y, acc[c + 1]));
    };
    auto region = [&](const uint4& q0, const uint4& q1, const uint4& q2, float wxy) {
      float w0 = wxy * wz0, w1 = wxy * wz1;
      acc2(q0.x, q1.z, w0, w1, 0);
      acc2(q0.y, q1.w, w0, w1, 2);
      acc2(q0.z, q2.x, w0, w1, 4);
      acc2(q0.w, q2.y, w0, w1, 6);
      acc2(q1.x, q2.z, w0, w1, 8);
      acc2(q1.y, q2.w, w0, w1, 10);
    };
    region(a0, a1, a2, wx0 * wy0);
    region(b0, b1, b2, wx0 * wy1);
    region(c0, c1, c2, wx1 * wy0);
    region(d0, d1, d2, wx1 * wy1);
    ++p;
  };
  gather(u[0], u[1], u[2]);
  float s[3], co[3];
#pragma unroll
  for (int d = 0; d < 3; ++d) { s[d] = sinf(u[d]); co[d] = cosf(u[d]); }
  for (int f = 0; f < 5; ++f) {
    gather(s[0], s[1], s[2]);
    gather(co[0], co[1], co[2]);
    if (f < 4) {
#pragma unroll
      for (int d = 0; d < 3; ++d) {
        float ns = 2.0f * s[d] * co[d];
        float nc = 1.0f - 2.0f * s[d] * s[d];
        s[d] = ns; co[d] = nc;
      }
    }
  }
  constexpr float inv = 1.0f / (float)P;
  float4 r0, r1, r2;
  r0.x = acc[0] * inv;  r0.y = acc[1] * inv;  r0.z = acc[2] * inv;  r0.w = acc[3] * inv;
  r1.x = acc[4] * inv;  r1.y = acc[5] * inv;  r1.z = acc[6] * inv;  r1.w = acc[7] * inv;
  r2.x = acc[8] * inv;  r2.y = acc[9] * inv;  r2.z = acc[10] * inv; r2.w = acc[11] * inv;
  float4* o4 = reinterpret_cast<float4*>(out + (size_t)n * C);
  o4[0] = r0; o4[1] = r1; o4[2] = r2;
}

// Last-resort naive fp32 path.
__global__ __launch_bounds__(256) void sample_naive_kernel(
    const float* __restrict__ xyz, const float* __restrict__ g,
    const float* __restrict__ xyz_min, const float* __restrict__ xyz_max,
    float* __restrict__ out, int N) {
  int n = blockIdx.x * 256 + threadIdx.x;
  if (n >= N) return;
  float u[3];
#pragma unroll
  for (int d = 0; d < 3; ++d) {
    float mn = xyz_min[d], mx = xyz_max[d];
    u[d] = (xyz[3 * (size_t)n + d] - mn) * (2.0f / (mx - mn)) - 1.0f;
  }
  float acc[C];
#pragma unroll
  for (int c = 0; c < C; ++c) acc[c] = 0.0f;
  int p = 0;
  auto gather = [&](float ex, float ey, float ez) {
    float e[3] = {ez, ey, ex};
    int i0[3], i1[3]; float w[3];
#pragma unroll
    for (int d = 0; d < 3; ++d) {
      float t = (e[d] + 1.0f) * (0.5f * (D - 1));
      int a = (int)floorf(t);
      a = a < 0 ? 0 : (a > D - 1 ? D - 1 : a);
      int b = a + 1 > D - 1 ? D - 1 : a + 1;
      i0[d] = a; i1[d] = b; w[d] = t - (float)a;
    }
    const float* gp = g + (size_t)p * C * VOX;
    auto corner = [&](int iz, int iy, int ix, float wgt) {
      int o = (ix * D + iy) * D + iz;
#pragma unroll
      for (int c = 0; c < C; ++c) acc[c] += wgt * gp[(size_t)c * VOX + o];
    };
    corner(i0[0], i0[1], i0[2], (1 - w[0]) * (1 - w[1]) * (1 - w[2]));
    corner(i1[0], i0[1], i0[2], w[0] * (1 - w[1]) * (1 - w[2]));
    corner(i0[0], i1[1], i0[2], (1 - w[0]) * w[1] * (1 - w[2]));
    corner(i1[0], i1[1], i0[2], w[0] * w[1] * (1 - w[2]));
    corner(i0[0], i0[1], i1[2], (1 - w[0]) * (1 - w[1]) * w[2]);
    corner(i1[0], i0[1], i1[2], w[0] * (1 - w[1]) * w[2]);
    corner(i0[0], i1[1], i1[2], (1 - w[0]) * w[1] * w[2]);
    corner(i1[0], i1[1], i1[2], w[0] * w[1] * w[2]);
    ++p;
  };
  gather(u[0], u[1], u[2]);
  float s[3], co[3];
#pragma unroll
  for (int d = 0; d < 3; ++d) { s[d] = sinf(u[d]); co[d] = cosf(u[d]); }
  for (int f = 0; f < 5; ++f) {
    gather(s[0], s[1], s[2]);
    gather(co[0], co[1], co[2]);
    if (f < 4) {
#pragma unroll
      for (int d = 0; d < 3; ++d) {
        float ns = 2.0f * s[d] * co[d];
        float nc = 1.0f - 2.0f * s[d] * s[d];
        s[d] = ns; co[d] = nc;
      }
    }
  }
  constexpr float inv = 1.0f / (float)P;
#pragma unroll
  for (int c = 0; c < C; ++c) out[(size_t)n * C + c] = acc[c] * inv;
}

extern "C" void kernel_launch(void* const* d_in, const int* in_sizes, int n_in,
                              void* d_out, int out_size, void* d_ws, size_t ws_size,
                              hipStream_t stream) {
  const float* xyz = (const float*)d_in[0];
  const float* grid = (const float*)d_in[1];
  const float* mn = (const float*)d_in[2];
  const float* mx = (const float*)d_in[3];
  float* out = (float*)d_out;
  int N = in_sizes[0] / 3;

  size_t gt_bytes = (size_t)P * VOX * C * sizeof(__half);   // ~233.6 MB
  size_t sorted_bytes = (size_t)N * sizeof(float4);         // 12.8 MB
  size_t cnt_bytes = (size_t)CELLS * sizeof(unsigned);      // 128 KB

  size_t need_sorted = sorted_bytes + gt_bytes + 2 * cnt_bytes + 1024;
  size_t need_min = gt_bytes + 256;

  int sblocks = (N + 255) / 256;
  int tblocks = (P * (VOX / 4) + 255) / 256;   // covers N too (2.43M > 800k)

  if (ws_size >= need_sorted) {
    char* w = (char*)d_ws;
    float4*   sorted  = (float4*)w;   w += sorted_bytes;
    __half*   gt      = (__half*)w;   w += gt_bytes;
    unsigned* counts  = (unsigned*)w; w += cnt_bytes;
    unsigned* offsets = (unsigned*)w;

    hipMemsetAsync(counts, 0, cnt_bytes, stream);
    transpose_count_kernel<<<tblocks, 256, 0, stream>>>(grid, gt, xyz, mn, mx,
                                                        counts, N);
    scan_kernel<<<1, 1024, 0, stream>>>(counts, offsets);
    scatter_kernel<<<sblocks, 256, 0, stream>>>(xyz, mn, mx, offsets, sorted, N);
    int pblocks = (N + 511) / 512;
    sample_pair_kernel<<<pblocks, 256, 0, stream>>>(sorted, gt, out, N);
  } else if (ws_size >= need_min) {
    __half* gt = (__half*)d_ws;
    transpose_count_kernel<<<tblocks, 256, 0, stream>>>(grid, gt, xyz, mn, mx,
                                                        nullptr, 0);
    sample_fp16_kernel<<<sblocks, 256, 0, stream>>>(xyz, gt, mn, mx, out, N);
  } else {
    sample_naive_kernel<<<sblocks, 256, 0, stream>>>(xyz, grid, mn, mx, out, N);
  }
}